// Round 1
// baseline (319.221 us; speedup 1.0000x reference)
//
#include <hip/hip_runtime.h>

// GaussianKernel: out[b,n,m] = exp(inv2s * (||Q[b,n]||^2 + ||KV[b,:,m]||^2 - 2*Q[b,n]·KV[b,:,m]))
// B=16, N=2048, M=2048, D=128, fp32 in/out.
//
// Strategy: memory-bound (256 MB output). Single-pass fp16 MFMA for the cross
// term (error budget: need exponent accurate to 0.02 at max element; fp16
// single-pass dot error std ~4.5e-3 -> ~4.4 sigma margin). Q_sq/K_sq in fp32.
// 128x128 tile, full K=128 staged once via global_load_lds(16B), no K-loop.

#define B_  16
#define N_  2048
#define M_  2048
#define D_  128

typedef _Float16 half8 __attribute__((ext_vector_type(8)));
typedef float    f32x4 __attribute__((ext_vector_type(4)));

// ---------------------------------------------------------------- prep Q ----
// One wave per row of 128: coalesced float2 loads, fp16 convert, shuffle-reduce sq.
__global__ __launch_bounds__(256) void prep_q(const float* __restrict__ Q,
                                              _Float16* __restrict__ Qh,
                                              float* __restrict__ Qsq) {
    const int row  = blockIdx.x * 4 + (threadIdx.x >> 6);
    const int lane = threadIdx.x & 63;
    const float2 v = reinterpret_cast<const float2*>(Q + (size_t)row * D_)[lane];
    float sq = v.x * v.x + v.y * v.y;
    union { _Float16 h[2]; unsigned int u; } pk;
    pk.h[0] = (_Float16)v.x;
    pk.h[1] = (_Float16)v.y;
    reinterpret_cast<unsigned int*>(Qh + (size_t)row * D_)[lane] = pk.u;
    #pragma unroll
    for (int off = 32; off > 0; off >>= 1) sq += __shfl_down(sq, off, 64);
    if (lane == 0) Qsq[row] = sq;
}

// --------------------------------------------------------------- prep KV ----
// KV[b, k, m] (m contiguous) -> KTh[b, m, k] fp16 (k contiguous) + Ksq[b, m].
// Thread owns one m-column: reads coalesced along m, writes 16B contiguous chunks.
__global__ __launch_bounds__(256) void prep_kv(const float* __restrict__ KV,
                                               _Float16* __restrict__ KTh,
                                               float* __restrict__ Ksq) {
    const int b = blockIdx.y;
    const int m = blockIdx.x * 256 + threadIdx.x;
    const float* src = KV + (size_t)b * D_ * M_ + m;
    _Float16*   dst = KTh + ((size_t)b * M_ + m) * D_;
    float sq = 0.f;
    #pragma unroll 2
    for (int k0 = 0; k0 < D_; k0 += 8) {
        union { _Float16 h[8]; int4 v; } buf;
        #pragma unroll
        for (int j = 0; j < 8; ++j) {
            const float v = src[(size_t)(k0 + j) * M_];
            sq += v * v;
            buf.h[j] = (_Float16)v;
        }
        *reinterpret_cast<int4*>(dst + k0) = buf.v;  // 16B, 16B-aligned
    }
    Ksq[(size_t)b * M_ + m] = sq;
}

// ------------------------------------------------------------------ GEMM ----
__global__ __launch_bounds__(256) void gauss_gemm(
    const _Float16* __restrict__ Qh, const _Float16* __restrict__ KTh,
    const float* __restrict__ Qsq,  const float* __restrict__ Ksq,
    const float* __restrict__ ls,   float* __restrict__ out) {
    __shared__ _Float16 Ash[128 * 128];   // 32 KB
    __shared__ _Float16 Bsh[128 * 128];   // 32 KB

    const int b    = blockIdx.y;
    const int bx   = blockIdx.x;
    const int n0   = (bx >> 4) << 7;      // Q-row tile base
    const int m0   = (bx & 15) << 7;      // KV-col tile base
    const int tid  = threadIdx.x;
    const int wave = tid >> 6;
    const int lane = tid & 63;

    const _Float16* Ag = Qh  + ((size_t)b * N_ + n0) * D_;
    const _Float16* Bg = KTh + ((size_t)b * M_ + m0) * D_;

    // Stage full 128x128 fp16 tiles: one instr = 64 lanes x 16B = 1024B = 4 rows.
    // LDS dest is wave-uniform base + lane*16 (no padding possible).
    #pragma unroll
    for (int i = 0; i < 8; ++i) {
        const int off = (wave * 8 + i) * 512;  // halves; 4-row chunk
        __builtin_amdgcn_global_load_lds(
            (const __attribute__((address_space(1))) unsigned int*)(Ag + off + lane * 8),
            (__attribute__((address_space(3))) unsigned int*)(&Ash[off]), 16, 0, 0);
        __builtin_amdgcn_global_load_lds(
            (const __attribute__((address_space(1))) unsigned int*)(Bg + off + lane * 8),
            (__attribute__((address_space(3))) unsigned int*)(&Bsh[off]), 16, 0, 0);
    }
    __syncthreads();

    // 2x2 wave grid, each wave computes 64x64 via 4x4 frags of 16x16.
    const int wr = (wave >> 1) * 64;
    const int wc = (wave & 1) * 64;
    const int lm = lane & 15;            // A-row / B-col within 16-tile
    const int lk = (lane >> 4) * 8;      // k offset within 32-step

    f32x4 acc[4][4] = {};
    #pragma unroll
    for (int ks = 0; ks < 128; ks += 32) {
        half8 af[4], bf[4];
        #pragma unroll
        for (int r = 0; r < 4; ++r)
            af[r] = *reinterpret_cast<const half8*>(&Ash[(wr + r * 16 + lm) * 128 + ks + lk]);
        #pragma unroll
        for (int c = 0; c < 4; ++c)
            bf[c] = *reinterpret_cast<const half8*>(&Bsh[(wc + c * 16 + lm) * 128 + ks + lk]);
        #pragma unroll
        for (int r = 0; r < 4; ++r)
            #pragma unroll
            for (int c = 0; c < 4; ++c)
                acc[r][c] = __builtin_amdgcn_mfma_f32_16x16x32_f16(af[r], bf[c], acc[r][c], 0, 0, 0);
    }

    // Epilogue: t = inv2s*(qsq + ksq - 2*dot); out = exp(t).
    const float inv2s = -0.5f * __expf(-2.0f * ls[0]);
    const int l4 = (lane >> 4) * 4;      // C row offset within 16-tile
    const float* qsq = Qsq + (size_t)b * N_ + n0;
    const float* ksq = Ksq + (size_t)b * M_ + m0;
    float* Cb = out + ((size_t)b * N_ + n0) * (size_t)M_ + m0;

    float ksv[4];
    #pragma unroll
    for (int c = 0; c < 4; ++c) ksv[c] = ksq[wc + c * 16 + lm];

    #pragma unroll
    for (int r = 0; r < 4; ++r) {
        #pragma unroll
        for (int i = 0; i < 4; ++i) {
            const int row  = wr + r * 16 + l4 + i;
            const float qv = qsq[row];
            float* Crow = Cb + (size_t)row * M_;
            #pragma unroll
            for (int c = 0; c < 4; ++c) {
                const float t = inv2s * (qv + ksv[c] - 2.0f * acc[r][c][i]);
                Crow[wc + c * 16 + lm] = __expf(t);
            }
        }
    }
}

// ---------------------------------------------------------------- launch ----
extern "C" void kernel_launch(void* const* d_in, const int* in_sizes, int n_in,
                              void* d_out, int out_size, void* d_ws, size_t ws_size,
                              hipStream_t stream) {
    const float* Q  = (const float*)d_in[0];
    const float* KV = (const float*)d_in[1];
    const float* ls = (const float*)d_in[2];
    float* out = (float*)d_out;

    // workspace layout: Qh 8MB | KTh 8MB | Qsq 128KB | Ksq 128KB  (16.25 MB)
    char* ws = (char*)d_ws;
    _Float16* Qh  = (_Float16*)ws;
    _Float16* KTh = (_Float16*)(ws + (size_t)8 * 1024 * 1024);
    float*    Qsq = (float*)(ws + (size_t)16 * 1024 * 1024);
    float*    Ksq = (float*)(ws + (size_t)16 * 1024 * 1024 + 128 * 1024);

    prep_q <<<dim3(B_ * N_ / 4), 256, 0, stream>>>(Q, Qh, Qsq);
    prep_kv<<<dim3(M_ / 256, B_), 256, 0, stream>>>(KV, KTh, Ksq);
    gauss_gemm<<<dim3(256, B_), 256, 0, stream>>>(Qh, KTh, Qsq, Ksq, ls, out);
}

// Round 2
// 318.578 us; speedup vs baseline: 1.0020x; 1.0020x over previous
//
#include <hip/hip_runtime.h>

// GaussianKernel: out[b,n,m] = exp(inv2s * (||Q[b,n]||^2 + ||KV[b,:,m]||^2 - 2*Q[b,n]·KV[b,:,m]))
// B=16, N=2048, M=2048, D=128, fp32 in/out.
//
// R1: epilogue LDS-transpose -> global_store_dwordx4 (full-line 512B segments),
//     XOR-swizzled A/B LDS staging (kills 16-way ds_read bank conflicts).

#define B_  16
#define N_  2048
#define M_  2048
#define D_  128

typedef _Float16 half8 __attribute__((ext_vector_type(8)));
typedef float    f32x4 __attribute__((ext_vector_type(4)));

// ---------------------------------------------------------------- prep Q ----
__global__ __launch_bounds__(256) void prep_q(const float* __restrict__ Q,
                                              _Float16* __restrict__ Qh,
                                              float* __restrict__ Qsq) {
    const int row  = blockIdx.x * 4 + (threadIdx.x >> 6);
    const int lane = threadIdx.x & 63;
    const float2 v = reinterpret_cast<const float2*>(Q + (size_t)row * D_)[lane];
    float sq = v.x * v.x + v.y * v.y;
    union { _Float16 h[2]; unsigned int u; } pk;
    pk.h[0] = (_Float16)v.x;
    pk.h[1] = (_Float16)v.y;
    reinterpret_cast<unsigned int*>(Qh + (size_t)row * D_)[lane] = pk.u;
    #pragma unroll
    for (int off = 32; off > 0; off >>= 1) sq += __shfl_down(sq, off, 64);
    if (lane == 0) Qsq[row] = sq;
}

// --------------------------------------------------------------- prep KV ----
// KV[b, k, m] -> KTh[b, m, k] fp16 + Ksq[b, m]. Reads coalesced along m.
__global__ __launch_bounds__(256) void prep_kv(const float* __restrict__ KV,
                                               _Float16* __restrict__ KTh,
                                               float* __restrict__ Ksq) {
    const int b = blockIdx.y;
    const int m = blockIdx.x * 256 + threadIdx.x;
    const float* src = KV + (size_t)b * D_ * M_ + m;
    _Float16*   dst = KTh + ((size_t)b * M_ + m) * D_;
    float sq = 0.f;
    #pragma unroll 2
    for (int k0 = 0; k0 < D_; k0 += 8) {
        union { _Float16 h[8]; int4 v; } buf;
        #pragma unroll
        for (int j = 0; j < 8; ++j) {
            const float v = src[(size_t)(k0 + j) * M_];
            sq += v * v;
            buf.h[j] = (_Float16)v;
        }
        *reinterpret_cast<int4*>(dst + k0) = buf.v;
    }
    Ksq[(size_t)b * M_ + m] = sq;
}

// ------------------------------------------------------------------ GEMM ----
// 128x128 tile per block, 4 waves (2x2 of 64x64), full K=128 staged once.
// LDS: A(32KB)+B(32KB) fp16 swizzled; C-stage (f32, stride 132) aliases them.
__global__ __launch_bounds__(256, 2) void gauss_gemm(
    const _Float16* __restrict__ Qh, const _Float16* __restrict__ KTh,
    const float* __restrict__ Qsq,  const float* __restrict__ Ksq,
    const float* __restrict__ ls,   float* __restrict__ out) {
    __shared__ __align__(16) char smem[132 * 128 * 4];   // 67584 B -> 2 blocks/CU
    _Float16* Ash = (_Float16*)smem;
    _Float16* Bsh = (_Float16*)(smem + 32768);

    const int b    = blockIdx.y;
    const int bx   = blockIdx.x;
    const int n0   = (bx >> 4) << 7;
    const int m0   = (bx & 15) << 7;
    const int tid  = threadIdx.x;
    const int wave = tid >> 6;
    const int lane = tid & 63;

    const _Float16* Ag = Qh  + ((size_t)b * N_ + n0) * D_;
    const _Float16* Bg = KTh + ((size_t)b * M_ + m0) * D_;

    // Stage 128x128 fp16 tiles with XOR swizzle: physical granule p (16B) of
    // row r holds logical granule g = p ^ (r&7). LDS dst stays wave-uniform
    // base + lane*16; the swizzle is applied on the GLOBAL address (permutes
    // 16B granules within each 256B row -> same coalescing).
    #pragma unroll
    for (int i = 0; i < 8; ++i) {
        const int chunk = wave * 8 + i;                 // 4 rows per chunk
        const int r     = chunk * 4 + (lane >> 4);      // physical row 0..127
        const int g     = (lane & 15) ^ (r & 7);        // logical granule
        const int goff  = r * 128 + g * 8;              // halves
        __builtin_amdgcn_global_load_lds(
            (const __attribute__((address_space(1))) unsigned int*)(Ag + goff),
            (__attribute__((address_space(3))) unsigned int*)(&Ash[chunk * 512]), 16, 0, 0);
        __builtin_amdgcn_global_load_lds(
            (const __attribute__((address_space(1))) unsigned int*)(Bg + goff),
            (__attribute__((address_space(3))) unsigned int*)(&Bsh[chunk * 512]), 16, 0, 0);
    }
    __syncthreads();

    const int wr = (wave >> 1) * 64;
    const int wc = (wave & 1) * 64;
    const int lm = lane & 15;
    const int kq = lane >> 4;            // k-quad: frag k-offset = kq*8
    const int sw = lm & 7;               // row&7 for all frag rows (row%8==lm%8)

    f32x4 acc[4][4] = {};
    #pragma unroll
    for (int ks = 0; ks < 128; ks += 32) {
        const int gl = (ks >> 3) + kq;   // logical granule of this fragment
        half8 af[4], bf[4];
        #pragma unroll
        for (int r = 0; r < 4; ++r)
            af[r] = *reinterpret_cast<const half8*>(
                &Ash[(wr + r * 16 + lm) * 128 + ((gl ^ sw) << 3)]);
        #pragma unroll
        for (int c = 0; c < 4; ++c)
            bf[c] = *reinterpret_cast<const half8*>(
                &Bsh[(wc + c * 16 + lm) * 128 + ((gl ^ sw) << 3)]);
        #pragma unroll
        for (int r = 0; r < 4; ++r)
            #pragma unroll
            for (int c = 0; c < 4; ++c)
                acc[r][c] = __builtin_amdgcn_mfma_f32_16x16x32_f16(af[r], bf[c], acc[r][c], 0, 0, 0);
    }

    // ------- epilogue: exp into padded f32 LDS stage, then coalesced x4 stores
    const float inv2s = -0.5f * __expf(-2.0f * ls[0]);
    const float cm2   = -2.0f * inv2s;
    const int l4 = (lane >> 4) * 4;
    const float* qsq = Qsq + (size_t)b * N_ + n0;
    const float* ksq = Ksq + (size_t)b * M_ + m0;

    float ksv[4];
    #pragma unroll
    for (int c = 0; c < 4; ++c) ksv[c] = ksq[wc + c * 16 + lm];
    float qsv[4][4];
    #pragma unroll
    for (int r = 0; r < 4; ++r)
        #pragma unroll
        for (int i = 0; i < 4; ++i) qsv[r][i] = qsq[wr + r * 16 + l4 + i];

    __syncthreads();                     // all A/B frag reads complete
    float* Csh = (float*)smem;           // 128 rows x stride 132 (conflict-free)

    #pragma unroll
    for (int r = 0; r < 4; ++r) {
        #pragma unroll
        for (int i = 0; i < 4; ++i) {
            const int row = wr + r * 16 + l4 + i;
            #pragma unroll
            for (int c = 0; c < 4; ++c) {
                const float t = fmaf(cm2, acc[r][c][i], inv2s * (qsv[r][i] + ksv[c]));
                Csh[row * 132 + wc + c * 16 + lm] = __expf(t);
            }
        }
    }
    __syncthreads();

    // Linear readback: wave instr = 2 rows x 512B contiguous full-line stores.
    float* Cb = out + ((size_t)b * N_ + n0) * (size_t)M_ + m0;
    const int trow = tid >> 5;           // 0..7
    const int tcol = (tid & 31) << 2;    // dword4 group
    #pragma unroll
    for (int it = 0; it < 16; ++it) {
        const int row = it * 8 + trow;
        const f32x4 v = *reinterpret_cast<const f32x4*>(&Csh[row * 132 + tcol]);
        *reinterpret_cast<f32x4*>(&Cb[(size_t)row * M_ + tcol]) = v;
    }
}

// ---------------------------------------------------------------- launch ----
extern "C" void kernel_launch(void* const* d_in, const int* in_sizes, int n_in,
                              void* d_out, int out_size, void* d_ws, size_t ws_size,
                              hipStream_t stream) {
    const float* Q  = (const float*)d_in[0];
    const float* KV = (const float*)d_in[1];
    const float* ls = (const float*)d_in[2];
    float* out = (float*)d_out;

    char* ws = (char*)d_ws;
    _Float16* Qh  = (_Float16*)ws;
    _Float16* KTh = (_Float16*)(ws + (size_t)8 * 1024 * 1024);
    float*    Qsq = (float*)(ws + (size_t)16 * 1024 * 1024);
    float*    Ksq = (float*)(ws + (size_t)16 * 1024 * 1024 + 128 * 1024);

    prep_q <<<dim3(B_ * N_ / 4), 256, 0, stream>>>(Q, Qh, Qsq);
    prep_kv<<<dim3(M_ / 256, B_), 256, 0, stream>>>(KV, KTh, Ksq);
    gauss_gemm<<<dim3(256, B_), 256, 0, stream>>>(Qh, KTh, Qsq, Ksq, ls, out);
}